// Round 9
// baseline (138.371 us; speedup 1.0000x reference)
//
#include <hip/hip_runtime.h>
#include <hip/hip_bf16.h>

#define NN 65536
#define EE 524288
#define BB 256
#define LL 64
#define HH 128
#define DD2 256
#define NEF 1024

typedef __attribute__((ext_vector_type(4))) float f32x4;
typedef __attribute__((ext_vector_type(8))) __bf16 bf16x8;

__device__ __forceinline__ void gload_lds16(const void* g, void* l) {
  __builtin_amdgcn_global_load_lds(
      (__attribute__((address_space(1))) void*)(g),
      (__attribute__((address_space(3))) void*)(l), 16, 0, 0);
}

// K1: fused z-path + weight conversions (unchanged from R8)
__global__ __launch_bounds__(256) void k1_prep(
    const float* __restrict__ z, const float* __restrict__ lattice,
    const float* __restrict__ W_lat, const float* __restrict__ b_lat,
    const float* __restrict__ W_en1, const float* __restrict__ b_en1,
    const float* __restrict__ W_en2, const float* __restrict__ b_en2,
    const float* __restrict__ W_st1, const float* __restrict__ b_st1,
    const float* __restrict__ W_st2, const float* __restrict__ b_st2,
    const float* __restrict__ W_nep, const float* __restrict__ W_nd1,
    const float* __restrict__ W_ed1,
    float* __restrict__ Zt, float* __restrict__ Zb, float* __restrict__ ZN,
    __bf16* __restrict__ Bp, __bf16* __restrict__ Bp2,
    float* __restrict__ out_en, float* __restrict__ out_st)
{
  int b = blockIdx.x, t = threadIdx.x;
  if (b < BB) {
    __shared__ float zl[70];
    __shared__ float zp[DD2];
    __shared__ float he[HH];
    __shared__ float hs[HH];
    if (t < LL) zl[t] = z[b*LL + t];
    else if (t < 70) zl[t] = lattice[t - LL];
    __syncthreads();
    {
      float acc = b_lat[t];
      #pragma unroll 4
      for (int k = 0; k < LL; ++k) acc = fmaf(zl[k], W_lat[k*DD2 + t], acc);
      zp[t] = fmaxf(acc, 0.f);
    }
    if (t < HH) {
      float a = b_en1[t];
      for (int k = 0; k < 70; ++k) a = fmaf(zl[k], W_en1[k*HH + t], a);
      he[t] = fmaxf(a, 0.f);
    } else {
      int tt = t - HH;
      float a = b_st1[tt];
      for (int k = 0; k < 70; ++k) a = fmaf(zl[k], W_st1[k*HH + tt], a);
      hs[tt] = fmaxf(a, 0.f);
    }
    __syncthreads();
    if (t < HH) {
      float a = 0.f, n = 0.f;
      #pragma unroll 4
      for (int k = 0; k < DD2; ++k) {
        a = fmaf(zp[k], W_ed1[k*HH + t], a);
        n = fmaf(zp[k], W_nd1[k*HH + t], n);
      }
      Zt[b*HH + t] = a;
      ZN[b*HH + t] = n;
    } else {
      int tt = t - HH;
      float a = 0.f;
      #pragma unroll 4
      for (int k = 0; k < DD2; ++k) a = fmaf(zp[k], W_ed1[(DD2 + k)*HH + tt], a);
      Zb[b*HH + tt] = a;
    }
    if (t < 2) {
      float a = b_en2[t];
      for (int k = 0; k < HH; ++k) a = fmaf(he[k], W_en2[k*2 + t], a);
      out_en[b*2 + t] = a;
    }
    if (t >= 32 && t < 41) {
      int c = t - 32;
      float a = b_st2[c];
      for (int k = 0; k < HH; ++k) a = fmaf(hs[k], W_st2[k*9 + c], a);
      out_st[b*9 + c] = a;
    }
  } else if (b < BB + 128) {           // W_nep (1024x256) -> Bp, kb = K-octet
    int kb = b - BB;                   // 0..127
    int col = t;
    bf16x8 v;
    #pragma unroll
    for (int j = 0; j < 8; ++j)
      v[j] = (__bf16)W_nep[(kb*8 + j)*256 + col];
    *(bf16x8*)(Bp + (kb*256 + col)*8) = v;
  } else {                             // W_nd1 (256x128) -> Bp2
    int kb = (b - BB - 128)*2 + (t >> 7);   // 0..31
    int col = t & 127;
    bf16x8 v;
    #pragma unroll
    for (int j = 0; j < 8; ++j)
      v[j] = (__bf16)W_nd1[(kb*8 + j)*128 + col];
    *(bf16x8*)(Bp2 + (kb*128 + col)*8) = v;
  }
}

// K3: R[gs][gd][c] = relu(Zt[gs]+Zb[gd]+b_ed1) @ W_ed2 + b_ed2   (256x256x3 table)
__global__ __launch_bounds__(256) void k3_rtab(
    const float* __restrict__ Zt, const float* __restrict__ Zb,
    const float* __restrict__ b_ed1, const float* __restrict__ W_ed2,
    const float* __restrict__ b_ed2, float* __restrict__ R)
{
  int gs = blockIdx.x, gd = threadIdx.x;
  __shared__ float zt_s[HH];
  __shared__ float b1_s[HH];
  __shared__ float w2_s[HH*3];
  if (gd < HH) {
    zt_s[gd] = Zt[gs*HH + gd];
    b1_s[gd] = b_ed1[gd];
    w2_s[gd] = W_ed2[gd];
    w2_s[gd + HH] = W_ed2[gd + HH];
    w2_s[gd + 2*HH] = W_ed2[gd + 2*HH];
  }
  __syncthreads();
  float a0 = b_ed2[0], a1 = b_ed2[1], a2 = b_ed2[2];
  const float* zbrow = Zb + gd*HH;
  #pragma unroll 4
  for (int k = 0; k < HH; ++k) {
    float h = fmaxf(zt_s[k] + zbrow[k] + b1_s[k], 0.f);
    a0 = fmaf(h, w2_s[k*3 + 0], a0);
    a1 = fmaf(h, w2_s[k*3 + 1], a1);
    a2 = fmaf(h, w2_s[k*3 + 2], a2);
  }
  float* o = R + (gs*256 + gd)*3;
  o[0] = a0; o[1] = a1; o[2] = a2;
}

// K4: recon_edge[e] = R[seg[src[e]]][seg[dst[e]]], 4 edges per thread
__global__ __launch_bounds__(256) void k4_edges(
    const int* __restrict__ src, const int* __restrict__ dst,
    const int* __restrict__ seg, const float* __restrict__ R,
    float* __restrict__ out_edge)
{
  int i = blockIdx.x*256 + threadIdx.x;              // 131072 threads
  int4 s4 = ((const int4*)src)[i];
  int4 d4 = ((const int4*)dst)[i];
  int b0 = (seg[s4.x]*256 + seg[d4.x])*3;
  int b1 = (seg[s4.y]*256 + seg[d4.y])*3;
  int b2 = (seg[s4.z]*256 + seg[d4.z])*3;
  int b3 = (seg[s4.w]*256 + seg[d4.w])*3;
  float r00 = R[b0], r01 = R[b0+1], r02 = R[b0+2];
  float r10 = R[b1], r11 = R[b1+1], r12 = R[b1+2];
  float r20 = R[b2], r21 = R[b2+1], r22 = R[b2+2];
  float r30 = R[b3], r31 = R[b3+1], r32 = R[b3+2];
  f32x4* o = (f32x4*)(out_edge + (size_t)i*12);
  f32x4 v0 = { r00, r01, r02, r10 };
  f32x4 v1 = { r11, r12, r20, r21 };
  f32x4 v2 = { r22, r30, r31, r32 };
  o[0] = v0; o[1] = v1; o[2] = v2;
}

// K5: fused node path, 8-phase-style schedule.
// 128 rows/block, 4 waves x 32 rows, grid 512. BK=64 K-tiles, B dbuf 2x32KB.
// Each tile = 4 phases of 16 MFMA: {ds_read 8 frags; stage 2 slices; barrier;
// lgkmcnt(0); setprio(1) MFMA setprio(0); barrier}. vmcnt(8) once per tile.
__global__ __launch_bounds__(256, 2) void k5_node(
    const float* __restrict__ node_emb, const __bf16* __restrict__ Bp,
    const __bf16* __restrict__ Bp2, const int* __restrict__ seg,
    const float* __restrict__ b_nep, const float* __restrict__ b_nd1,
    const float* __restrict__ W_nd2, const float* __restrict__ b_nd2,
    const float* __restrict__ ZN, float* __restrict__ out_node)
{
  // union: B dbuf 2 x 32KB (64KB) / nep tile 128 x 264 bf16 (67584B)
  __shared__ __align__(16) char lds_raw[67584];
  __bf16* Bs    = (__bf16*)lds_raw;
  __bf16* nep_s = (__bf16*)lds_raw;

  const int tid = threadIdx.x;
  const int w = tid >> 6;
  const int l = tid & 63;
  const int l15 = l & 15;
  const int g4 = l >> 4;
  const int wr0 = blockIdx.x*128 + w*32;

  f32x4 acc[2][16];
  const f32x4 fzero = {0.f, 0.f, 0.f, 0.f};
  #pragma unroll
  for (int rt = 0; rt < 2; ++rt)
    #pragma unroll
    for (int t = 0; t < 16; ++t) acc[rt][t] = fzero;

  const float* arow0 = node_emb + (size_t)(wr0 + l15)*NEF + g4*8;
  const float* arow1 = arow0 + (size_t)16*NEF;

  f32x4 aE[8], aO[8];          // E/O A register sets: [rt*4 + ko*2 + half]

  #define STAGE2(T, I0)                                                         \
  {                                                                             \
    int ksrc = (T) > 15 ? 15 : (T);                                             \
    const __bf16* bsrc = Bp + (size_t)ksrc*16384 + tid*8;                       \
    __bf16* bdst = Bs + (size_t)((T) & 1)*16384 + tid*8;                        \
    gload_lds16(bsrc + (I0)*2048,     bdst + (I0)*2048);                        \
    gload_lds16(bsrc + ((I0)+1)*2048, bdst + ((I0)+1)*2048);                    \
  }

  #define LOAD_A(T, S)                                                          \
  {                                                                             \
    int kA = (T) > 15 ? 15 : (T);                                               \
    _Pragma("unroll")                                                           \
    for (int rt = 0; rt < 2; ++rt) {                                            \
      const float* ar = rt ? arow1 : arow0;                                     \
      _Pragma("unroll")                                                         \
      for (int ko = 0; ko < 2; ++ko) {                                          \
        S[rt*4 + ko*2 + 0] = *(const f32x4*)(ar + kA*64 + ko*32);               \
        S[rt*4 + ko*2 + 1] = *(const f32x4*)(ar + kA*64 + ko*32 + 4);           \
      }                                                                         \
    }                                                                           \
  }

  #define CVT8(DST, LO, HI)                                                     \
  { f32x4 lo_ = (LO), hi_ = (HI);                                               \
    DST[0]=(__bf16)lo_[0]; DST[1]=(__bf16)lo_[1]; DST[2]=(__bf16)lo_[2]; DST[3]=(__bf16)lo_[3]; \
    DST[4]=(__bf16)hi_[0]; DST[5]=(__bf16)hi_[1]; DST[6]=(__bf16)hi_[2]; DST[7]=(__bf16)hi_[3]; }

  // one phase: read 8 B frags (cluster KO/TTB), stage 2 slices of tile T+1,
  // optional PRE (A-loads), barrier, lgkmcnt(0), prio MFMA, optional vmcnt, barrier
  #define PHASE(T, J, KO, TTB, AALO, AAHI, PRE, POST)                           \
  {                                                                             \
    bf16x8 f[8];                                                                \
    const bf16x8* Bq = (const bf16x8*)(Bs + (size_t)((T) & 1)*16384)            \
                       + ((KO)*4 + g4)*256 + l15;                               \
    _Pragma("unroll")                                                           \
    for (int q = 0; q < 8; ++q) f[q] = Bq[((TTB) + q)*16];                      \
    STAGE2((T) + 1, (J)*2);                                                     \
    PRE                                                                         \
    __builtin_amdgcn_sched_barrier(0);                                          \
    __builtin_amdgcn_s_barrier();                                               \
    asm volatile("s_waitcnt lgkmcnt(0)" ::: "memory");                          \
    __builtin_amdgcn_sched_barrier(0);                                          \
    __builtin_amdgcn_s_setprio(1);                                              \
    _Pragma("unroll")                                                           \
    for (int q = 0; q < 8; ++q) {                                               \
      acc[0][(TTB)+q] = __builtin_amdgcn_mfma_f32_16x16x32_bf16(AALO, f[q], acc[0][(TTB)+q], 0, 0, 0); \
      acc[1][(TTB)+q] = __builtin_amdgcn_mfma_f32_16x16x32_bf16(AAHI, f[q], acc[1][(TTB)+q], 0, 0, 0); \
    }                                                                           \
    __builtin_amdgcn_s_setprio(0);                                              \
    POST                                                                        \
    __builtin_amdgcn_sched_barrier(0);                                          \
    __builtin_amdgcn_s_barrier();                                               \
  }

  #define TILE(T, S)                                                            \
  {                                                                             \
    bf16x8 aa0, aa1, aa2, aa3;                                                  \
    CVT8(aa0, S[0], S[1]); CVT8(aa2, S[4], S[5]);                               \
    PHASE(T, 0, 0, 0, aa0, aa2, , )                                             \
    PHASE(T, 1, 0, 8, aa0, aa2, , )                                             \
    CVT8(aa1, S[2], S[3]); CVT8(aa3, S[6], S[7]);                               \
    PHASE(T, 2, 1, 0, aa1, aa3, , )                                             \
    PHASE(T, 3, 1, 8, aa1, aa3,                                                 \
          LOAD_A((T) + 2, S);,                                                  \
          asm volatile("s_waitcnt vmcnt(8)" ::: "memory");)                     \
  }

  // ---- prologue: stage tile 0 fully; load A(0)->E, A(1)->O; drain stage; barrier
  STAGE2(0, 0); STAGE2(0, 2); STAGE2(0, 4); STAGE2(0, 6);
  __builtin_amdgcn_sched_barrier(0);
  LOAD_A(0, aE);
  LOAD_A(1, aO);
  __builtin_amdgcn_sched_barrier(0);
  asm volatile("s_waitcnt vmcnt(16)" ::: "memory");   // stage(0) done; A(0),A(1) may fly
  __builtin_amdgcn_s_barrier();
  __builtin_amdgcn_sched_barrier(0);

  for (int kk = 0; kk < 16; kk += 2) {
    TILE(kk,     aE);
    TILE(kk + 1, aO);
  }
  #undef TILE
  #undef PHASE
  #undef CVT8
  #undef LOAD_A
  #undef STAGE2

  // drain trailing stage + A loads before nep_s overwrites the union
  asm volatile("s_waitcnt vmcnt(0)" ::: "memory");
  __syncthreads();

  // epilogue 1: nep = relu(acc + b_nep) -> LDS (bf16), wave-private rows
  #pragma unroll
  for (int rt = 0; rt < 2; ++rt)
    #pragma unroll
    for (int t = 0; t < 16; ++t) {
      int col = t*16 + l15;
      float bn = b_nep[col];
      #pragma unroll
      for (int r = 0; r < 4; ++r) {
        float v = fmaxf(acc[rt][t][r] + bn, 0.f);
        int row = w*32 + rt*16 + g4*4 + r;
        nep_s[row*264 + col] = (__bf16)v;
      }
    }

  // GEMM2: h-pre = nep @ W_nd1 (K=256), cols 0..127 (B fragments from L2)
  f32x4 acc2[2][8];
  #pragma unroll
  for (int rt = 0; rt < 2; ++rt)
    #pragma unroll
    for (int t = 0; t < 8; ++t) acc2[rt][t] = fzero;
  const __bf16* nrow0 = nep_s + (w*32 + l15)*264 + g4*8;
  const __bf16* nrow1 = nrow0 + 16*264;
  #pragma unroll 2
  for (int kk = 0; kk < 8; ++kk) {
    bf16x8 a20 = *(const bf16x8*)(nrow0 + kk*32);
    bf16x8 a21 = *(const bf16x8*)(nrow1 + kk*32);
    #pragma unroll
    for (int t = 0; t < 8; ++t) {
      bf16x8 b2 = *(const bf16x8*)(Bp2 + ((kk*4 + g4)*128 + t*16 + l15)*8);
      acc2[0][t] = __builtin_amdgcn_mfma_f32_16x16x32_bf16(a20, b2, acc2[0][t], 0, 0, 0);
      acc2[1][t] = __builtin_amdgcn_mfma_f32_16x16x32_bf16(a21, b2, acc2[1][t], 0, 0, 0);
    }
  }

  // epilogue 2: h = relu(acc2 + ZN[seg[row]] + b_nd1); recon = h @ W_nd2 + b_nd2
  f32x4 bn2 = *(const f32x4*)b_nd2;
  #pragma unroll
  for (int rt = 0; rt < 2; ++rt) {
    int sid[4];
    #pragma unroll
    for (int r = 0; r < 4; ++r) sid[r] = seg[wr0 + rt*16 + g4*4 + r];
    float p[4][4];
    #pragma unroll
    for (int r = 0; r < 4; ++r)
      #pragma unroll
      for (int c = 0; c < 4; ++c) p[r][c] = 0.f;
    #pragma unroll
    for (int t = 0; t < 8; ++t) {
      int col = t*16 + l15;
      float b1 = b_nd1[col];
      f32x4 w2 = *(const f32x4*)(W_nd2 + col*4);
      #pragma unroll
      for (int r = 0; r < 4; ++r) {
        float h = fmaxf(acc2[rt][t][r] + ZN[sid[r]*HH + col] + b1, 0.f);
        p[r][0] = fmaf(h, w2[0], p[r][0]);
        p[r][1] = fmaf(h, w2[1], p[r][1]);
        p[r][2] = fmaf(h, w2[2], p[r][2]);
        p[r][3] = fmaf(h, w2[3], p[r][3]);
      }
    }
    #pragma unroll
    for (int off = 1; off < 16; off <<= 1)
      #pragma unroll
      for (int r = 0; r < 4; ++r)
        #pragma unroll
        for (int c = 0; c < 4; ++c)
          p[r][c] += __shfl_xor(p[r][c], off, 64);
    if (l15 == 0) {
      #pragma unroll
      for (int r = 0; r < 4; ++r) {
        f32x4 v = { p[r][0] + bn2[0], p[r][1] + bn2[1], p[r][2] + bn2[2], p[r][3] + bn2[3] };
        *(f32x4*)(out_node + (size_t)(wr0 + rt*16 + g4*4 + r)*4) = v;
      }
    }
  }
}

extern "C" void kernel_launch(void* const* d_in, const int* in_sizes, int n_in,
                              void* d_out, int out_size, void* d_ws, size_t ws_size,
                              hipStream_t stream) {
  const float* z        = (const float*)d_in[0];
  const float* node_emb = (const float*)d_in[1];
  const float* lattice  = (const float*)d_in[2];
  const int*   seg      = (const int*)d_in[3];
  const int*   src      = (const int*)d_in[4];
  const int*   dst      = (const int*)d_in[5];
  const float* W_lat    = (const float*)d_in[6];
  const float* b_lat    = (const float*)d_in[7];
  const float* W_nep    = (const float*)d_in[8];
  const float* b_nep    = (const float*)d_in[9];
  const float* W_nd1    = (const float*)d_in[10];
  const float* b_nd1    = (const float*)d_in[11];
  const float* W_nd2    = (const float*)d_in[12];
  const float* b_nd2    = (const float*)d_in[13];
  const float* W_ed1    = (const float*)d_in[14];
  const float* b_ed1    = (const float*)d_in[15];
  const float* W_ed2    = (const float*)d_in[16];
  const float* b_ed2    = (const float*)d_in[17];
  const float* W_en1    = (const float*)d_in[18];
  const float* b_en1    = (const float*)d_in[19];
  const float* W_en2    = (const float*)d_in[20];
  const float* b_en2    = (const float*)d_in[21];
  const float* W_st1    = (const float*)d_in[22];
  const float* b_st1    = (const float*)d_in[23];
  const float* W_st2    = (const float*)d_in[24];
  const float* b_st2    = (const float*)d_in[25];

  char* ws = (char*)d_ws;
  float*  Zt    = (float*)(ws + 0);          // 131072
  float*  Zb    = (float*)(ws + 131072);     // 131072
  float*  ZN    = (float*)(ws + 262144);     // 131072
  float*  Rt    = (float*)(ws + 393216);     // 786432
  __bf16* Bp    = (__bf16*)(ws + 1179648);   // 524288
  __bf16* Bp2   = (__bf16*)(ws + 1703936);   // 65536

  float* out_node = (float*)d_out;                 // 65536*4
  float* out_edge = out_node + 262144;             // 524288*3
  float* out_en   = out_node + 1835008;            // 256*2
  float* out_st   = out_node + 1835520;            // 256*9

  hipLaunchKernelGGL(k1_prep, dim3(400), dim3(256), 0, stream,
                     z, lattice, W_lat, b_lat, W_en1, b_en1, W_en2, b_en2,
                     W_st1, b_st1, W_st2, b_st2, W_nep, W_nd1, W_ed1,
                     Zt, Zb, ZN, Bp, Bp2, out_en, out_st);
  hipLaunchKernelGGL(k3_rtab, dim3(256), dim3(256), 0, stream,
                     Zt, Zb, b_ed1, W_ed2, b_ed2, Rt);
  hipLaunchKernelGGL(k4_edges, dim3(512), dim3(256), 0, stream,
                     src, dst, seg, Rt, out_edge);
  hipLaunchKernelGGL(k5_node, dim3(512), dim3(256), 0, stream,
                     node_emb, Bp, Bp2, seg, b_nep, b_nd1, W_nd2, b_nd2, ZN, out_node);
}

// Round 10
// 114.153 us; speedup vs baseline: 1.2122x; 1.2122x over previous
//
#include <hip/hip_runtime.h>
#include <hip/hip_bf16.h>

#define NN 65536
#define EE 524288
#define BB 256
#define LL 64
#define HH 128
#define DD2 256
#define NEF 1024

typedef __attribute__((ext_vector_type(4))) float f32x4;
typedef __attribute__((ext_vector_type(8))) __bf16 bf16x8;

__device__ __forceinline__ void gload_lds16(const void* g, void* l) {
  __builtin_amdgcn_global_load_lds(
      (__attribute__((address_space(1))) void*)(g),
      (__attribute__((address_space(3))) void*)(l), 16, 0, 0);
}

// K1: fused z-path + weight conversions (unchanged)
__global__ __launch_bounds__(256) void k1_prep(
    const float* __restrict__ z, const float* __restrict__ lattice,
    const float* __restrict__ W_lat, const float* __restrict__ b_lat,
    const float* __restrict__ W_en1, const float* __restrict__ b_en1,
    const float* __restrict__ W_en2, const float* __restrict__ b_en2,
    const float* __restrict__ W_st1, const float* __restrict__ b_st1,
    const float* __restrict__ W_st2, const float* __restrict__ b_st2,
    const float* __restrict__ W_nep, const float* __restrict__ W_nd1,
    const float* __restrict__ W_ed1,
    float* __restrict__ Zt, float* __restrict__ Zb, float* __restrict__ ZN,
    __bf16* __restrict__ Bp, __bf16* __restrict__ Bp2,
    float* __restrict__ out_en, float* __restrict__ out_st)
{
  int b = blockIdx.x, t = threadIdx.x;
  if (b < BB) {
    __shared__ float zl[70];
    __shared__ float zp[DD2];
    __shared__ float he[HH];
    __shared__ float hs[HH];
    if (t < LL) zl[t] = z[b*LL + t];
    else if (t < 70) zl[t] = lattice[t - LL];
    __syncthreads();
    {
      float acc = b_lat[t];
      #pragma unroll 4
      for (int k = 0; k < LL; ++k) acc = fmaf(zl[k], W_lat[k*DD2 + t], acc);
      zp[t] = fmaxf(acc, 0.f);
    }
    if (t < HH) {
      float a = b_en1[t];
      for (int k = 0; k < 70; ++k) a = fmaf(zl[k], W_en1[k*HH + t], a);
      he[t] = fmaxf(a, 0.f);
    } else {
      int tt = t - HH;
      float a = b_st1[tt];
      for (int k = 0; k < 70; ++k) a = fmaf(zl[k], W_st1[k*HH + tt], a);
      hs[tt] = fmaxf(a, 0.f);
    }
    __syncthreads();
    if (t < HH) {
      float a = 0.f, n = 0.f;
      #pragma unroll 4
      for (int k = 0; k < DD2; ++k) {
        a = fmaf(zp[k], W_ed1[k*HH + t], a);
        n = fmaf(zp[k], W_nd1[k*HH + t], n);
      }
      Zt[b*HH + t] = a;
      ZN[b*HH + t] = n;
    } else {
      int tt = t - HH;
      float a = 0.f;
      #pragma unroll 4
      for (int k = 0; k < DD2; ++k) a = fmaf(zp[k], W_ed1[(DD2 + k)*HH + tt], a);
      Zb[b*HH + tt] = a;
    }
    if (t < 2) {
      float a = b_en2[t];
      for (int k = 0; k < HH; ++k) a = fmaf(he[k], W_en2[k*2 + t], a);
      out_en[b*2 + t] = a;
    }
    if (t >= 32 && t < 41) {
      int c = t - 32;
      float a = b_st2[c];
      for (int k = 0; k < HH; ++k) a = fmaf(hs[k], W_st2[k*9 + c], a);
      out_st[b*9 + c] = a;
    }
  } else if (b < BB + 128) {           // W_nep (1024x256) -> Bp, kb = K-octet
    int kb = b - BB;                   // 0..127
    int col = t;
    bf16x8 v;
    #pragma unroll
    for (int j = 0; j < 8; ++j)
      v[j] = (__bf16)W_nep[(kb*8 + j)*256 + col];
    *(bf16x8*)(Bp + (kb*256 + col)*8) = v;
  } else {                             // W_nd1 (256x128) -> Bp2
    int kb = (b - BB - 128)*2 + (t >> 7);   // 0..31
    int col = t & 127;
    bf16x8 v;
    #pragma unroll
    for (int j = 0; j < 8; ++j)
      v[j] = (__bf16)W_nd1[(kb*8 + j)*128 + col];
    *(bf16x8*)(Bp2 + (kb*128 + col)*8) = v;
  }
}

// K3: R[gs][gd][c] = relu(Zt[gs]+Zb[gd]+b_ed1) @ W_ed2 + b_ed2   (256x256x3 table)
__global__ __launch_bounds__(256) void k3_rtab(
    const float* __restrict__ Zt, const float* __restrict__ Zb,
    const float* __restrict__ b_ed1, const float* __restrict__ W_ed2,
    const float* __restrict__ b_ed2, float* __restrict__ R)
{
  int gs = blockIdx.x, gd = threadIdx.x;
  __shared__ float zt_s[HH];
  __shared__ float b1_s[HH];
  __shared__ float w2_s[HH*3];
  if (gd < HH) {
    zt_s[gd] = Zt[gs*HH + gd];
    b1_s[gd] = b_ed1[gd];
    w2_s[gd] = W_ed2[gd];
    w2_s[gd + HH] = W_ed2[gd + HH];
    w2_s[gd + 2*HH] = W_ed2[gd + 2*HH];
  }
  __syncthreads();
  float a0 = b_ed2[0], a1 = b_ed2[1], a2 = b_ed2[2];
  const float* zbrow = Zb + gd*HH;
  #pragma unroll 4
  for (int k = 0; k < HH; ++k) {
    float h = fmaxf(zt_s[k] + zbrow[k] + b1_s[k], 0.f);
    a0 = fmaf(h, w2_s[k*3 + 0], a0);
    a1 = fmaf(h, w2_s[k*3 + 1], a1);
    a2 = fmaf(h, w2_s[k*3 + 2], a2);
  }
  float* o = R + (gs*256 + gd)*3;
  o[0] = a0; o[1] = a1; o[2] = a2;
}

// K4: recon_edge[e] = R[seg[src[e]]][seg[dst[e]]], 4 edges per thread
__global__ __launch_bounds__(256) void k4_edges(
    const int* __restrict__ src, const int* __restrict__ dst,
    const int* __restrict__ seg, const float* __restrict__ R,
    float* __restrict__ out_edge)
{
  int i = blockIdx.x*256 + threadIdx.x;              // 131072 threads
  int4 s4 = ((const int4*)src)[i];
  int4 d4 = ((const int4*)dst)[i];
  int b0 = (seg[s4.x]*256 + seg[d4.x])*3;
  int b1 = (seg[s4.y]*256 + seg[d4.y])*3;
  int b2 = (seg[s4.z]*256 + seg[d4.z])*3;
  int b3 = (seg[s4.w]*256 + seg[d4.w])*3;
  float r00 = R[b0], r01 = R[b0+1], r02 = R[b0+2];
  float r10 = R[b1], r11 = R[b1+1], r12 = R[b1+2];
  float r20 = R[b2], r21 = R[b2+1], r22 = R[b2+2];
  float r30 = R[b3], r31 = R[b3+1], r32 = R[b3+2];
  f32x4* o = (f32x4*)(out_edge + (size_t)i*12);
  f32x4 v0 = { r00, r01, r02, r10 };
  f32x4 v1 = { r11, r12, r20, r21 };
  f32x4 v2 = { r22, r30, r31, r32 };
  o[0] = v0; o[1] = v1; o[2] = v2;
}

// K5: fused node path, occupancy-first restructure.
// 512 threads / 8 waves (4 row-groups x 2 col-halves); wave = 32r x 128c -> acc 64 VGPR.
// Both A (f32, XOR-swizzled) and B staged to LDS per BK=32 step, double-buffered.
// One vmcnt(0)+barrier per step. 2 blocks/CU, 4 waves/SIMD, grid 512 = 1 generation.
__global__ __launch_bounds__(512, 4) void k5_node(
    const float* __restrict__ node_emb, const __bf16* __restrict__ Bp,
    const __bf16* __restrict__ Bp2, const int* __restrict__ seg,
    const float* __restrict__ b_nep, const float* __restrict__ b_nd1,
    const float* __restrict__ W_nd2, const float* __restrict__ b_nd2,
    const float* __restrict__ ZN, float* __restrict__ out_node)
{
  // union: staging dbuf 2 x (A 16KB + B 16KB) = 64KB / nep tile 128 x 264 bf16 = 67584B
  __shared__ __align__(16) char lds_raw[67584];
  __bf16* nep_s = (__bf16*)lds_raw;

  const int tid = threadIdx.x;           // 0..511
  const int w   = tid >> 6;              // 0..7
  const int l15 = tid & 15;
  const int g4  = (tid >> 4) & 3;        // K-octet group
  const int wr  = w >> 1;                // row-group 0..3
  const int wc  = w & 1;                 // col-half 0..1
  const int rowbase = blockIdx.x * 128;

  f32x4 acc[2][8];
  const f32x4 fzero = {0.f, 0.f, 0.f, 0.f};
  #pragma unroll
  for (int rt = 0; rt < 2; ++rt)
    #pragma unroll
    for (int ct = 0; ct < 8; ++ct) acc[rt][ct] = fzero;

  // A staging source pre-swizzle: physical LDS byte P = tid*16 (+8192*i),
  // logical byte = P ^ ((row&7)<<4), row = P>>7 = (tid>>3)+64i.
  const int arow_t = tid >> 3;                         // 0..63
  const int aoff   = (((tid & 7) ^ (arow_t & 7)) << 2); // f32 idx within row-step
  const int axor   = (l15 & 7) << 4;                   // read-side swizzle

  #define CVT8(DST, LO, HI)                                                     \
  { f32x4 lo_ = (LO), hi_ = (HI);                                               \
    DST[0]=(__bf16)lo_[0]; DST[1]=(__bf16)lo_[1]; DST[2]=(__bf16)lo_[2]; DST[3]=(__bf16)lo_[3]; \
    DST[4]=(__bf16)hi_[0]; DST[5]=(__bf16)hi_[1]; DST[6]=(__bf16)hi_[2]; DST[7]=(__bf16)hi_[3]; }

  #define STAGE(KB, C)                                                          \
  {                                                                             \
    int kb_ = (KB) > 31 ? 31 : (KB);                                            \
    char* Ad = lds_raw + (C)*32768;                                             \
    char* Bd = Ad + 16384;                                                      \
    const float* asrc = node_emb + (size_t)rowbase*NEF + kb_*32 + aoff;         \
    gload_lds16(asrc + (size_t)arow_t*NEF,        Ad + tid*16);                 \
    gload_lds16(asrc + (size_t)(arow_t + 64)*NEF, Ad + tid*16 + 8192);          \
    const __bf16* bsrc = Bp + (size_t)kb_*8192 + tid*8;                         \
    gload_lds16(bsrc,        Bd + tid*16);                                      \
    gload_lds16(bsrc + 4096, Bd + tid*16 + 8192);                               \
  }

  // ---- prologue: stage step 0 -> buf0; drain; barrier
  STAGE(0, 0);
  __builtin_amdgcn_sched_barrier(0);
  asm volatile("s_waitcnt vmcnt(0)" ::: "memory");
  __builtin_amdgcn_s_barrier();
  __builtin_amdgcn_sched_barrier(0);

  #pragma unroll 2
  for (int kk = 0; kk < 32; ++kk) {
    const int c = kk & 1;
    // stage next step into the other buffer
    STAGE(kk + 1, c ^ 1);
    __builtin_amdgcn_sched_barrier(0);
    // compute from buf c
    const char* Ab = lds_raw + c*32768;
    const char* Bb = Ab + 16384;
    int p0 = (((wr*32 + l15)*128)      + g4*32) ^ axor;
    int p1 = (((wr*32 + 16 + l15)*128) + g4*32) ^ axor;
    f32x4 a00 = *(const f32x4*)(Ab + p0);
    f32x4 a01 = *(const f32x4*)(Ab + (p0 ^ 16));
    f32x4 a10 = *(const f32x4*)(Ab + p1);
    f32x4 a11 = *(const f32x4*)(Ab + (p1 ^ 16));
    bf16x8 aa0, aa1;
    CVT8(aa0, a00, a01);
    CVT8(aa1, a10, a11);
    const bf16x8* Bv = (const bf16x8*)Bb;
    #pragma unroll
    for (int ct = 0; ct < 8; ++ct) {
      bf16x8 bfr = Bv[g4*256 + wc*128 + ct*16 + l15];
      acc[0][ct] = __builtin_amdgcn_mfma_f32_16x16x32_bf16(aa0, bfr, acc[0][ct], 0, 0, 0);
      acc[1][ct] = __builtin_amdgcn_mfma_f32_16x16x32_bf16(aa1, bfr, acc[1][ct], 0, 0, 0);
    }
    __builtin_amdgcn_sched_barrier(0);
    asm volatile("s_waitcnt vmcnt(0)" ::: "memory");   // next buf staged
    __builtin_amdgcn_s_barrier();
    __builtin_amdgcn_sched_barrier(0);
  }
  #undef STAGE

  __syncthreads();

  // epilogue 1: nep = relu(acc + b_nep) -> LDS (bf16)
  #pragma unroll
  for (int rt = 0; rt < 2; ++rt)
    #pragma unroll
    for (int ct = 0; ct < 8; ++ct) {
      int col = wc*128 + ct*16 + l15;
      float bn = b_nep[col];
      #pragma unroll
      for (int r = 0; r < 4; ++r) {
        float v = fmaxf(acc[rt][ct][r] + bn, 0.f);
        int row = wr*32 + rt*16 + g4*4 + r;
        nep_s[row*264 + col] = (__bf16)v;
      }
    }
  __syncthreads();   // cross-wave: GEMM2 reads other waves' nep rows

  // GEMM2: h-pre = nep @ W_nd1 (K=256); wave w owns rows w*16..w*16+15
  f32x4 acc2[8];
  #pragma unroll
  for (int t = 0; t < 8; ++t) acc2[t] = fzero;
  const __bf16* nrow = nep_s + (w*16 + l15)*264 + g4*8;
  #pragma unroll 2
  for (int kk = 0; kk < 8; ++kk) {
    bf16x8 a2 = *(const bf16x8*)(nrow + kk*32);
    #pragma unroll
    for (int t = 0; t < 8; ++t) {
      bf16x8 b2 = *(const bf16x8*)(Bp2 + ((kk*4 + g4)*128 + t*16 + l15)*8);
      acc2[t] = __builtin_amdgcn_mfma_f32_16x16x32_bf16(a2, b2, acc2[t], 0, 0, 0);
    }
  }

  // epilogue 2: h = relu(acc2 + ZN[seg[row]] + b_nd1); recon = h @ W_nd2 + b_nd2
  int sid[4];
  #pragma unroll
  for (int r = 0; r < 4; ++r) sid[r] = seg[rowbase + w*16 + g4*4 + r];
  float p[4][4];
  #pragma unroll
  for (int r = 0; r < 4; ++r)
    #pragma unroll
    for (int c2 = 0; c2 < 4; ++c2) p[r][c2] = 0.f;
  #pragma unroll
  for (int t = 0; t < 8; ++t) {
    int col = t*16 + l15;
    float b1 = b_nd1[col];
    f32x4 w2 = *(const f32x4*)(W_nd2 + col*4);
    #pragma unroll
    for (int r = 0; r < 4; ++r) {
      float h = fmaxf(acc2[t][r] + ZN[sid[r]*HH + col] + b1, 0.f);
      p[r][0] = fmaf(h, w2[0], p[r][0]);
      p[r][1] = fmaf(h, w2[1], p[r][1]);
      p[r][2] = fmaf(h, w2[2], p[r][2]);
      p[r][3] = fmaf(h, w2[3], p[r][3]);
    }
  }
  #pragma unroll
  for (int off = 1; off < 16; off <<= 1)
    #pragma unroll
    for (int r = 0; r < 4; ++r)
      #pragma unroll
      for (int c2 = 0; c2 < 4; ++c2)
        p[r][c2] += __shfl_xor(p[r][c2], off, 64);
  if (l15 == 0) {
    f32x4 bn2 = *(const f32x4*)b_nd2;
    #pragma unroll
    for (int r = 0; r < 4; ++r) {
      f32x4 v = { p[r][0] + bn2[0], p[r][1] + bn2[1], p[r][2] + bn2[2], p[r][3] + bn2[3] };
      *(f32x4*)(out_node + (size_t)(rowbase + w*16 + g4*4 + r)*4) = v;
    }
  }
  #undef CVT8
}

extern "C" void kernel_launch(void* const* d_in, const int* in_sizes, int n_in,
                              void* d_out, int out_size, void* d_ws, size_t ws_size,
                              hipStream_t stream) {
  const float* z        = (const float*)d_in[0];
  const float* node_emb = (const float*)d_in[1];
  const float* lattice  = (const float*)d_in[2];
  const int*   seg      = (const int*)d_in[3];
  const int*   src      = (const int*)d_in[4];
  const int*   dst      = (const int*)d_in[5];
  const float* W_lat    = (const float*)d_in[6];
  const float* b_lat    = (const float*)d_in[7];
  const float* W_nep    = (const float*)d_in[8];
  const float* b_nep    = (const float*)d_in[9];
  const float* W_nd1    = (const float*)d_in[10];
  const float* b_nd1    = (const float*)d_in[11];
  const float* W_nd2    = (const float*)d_in[12];
  const float* b_nd2    = (const float*)d_in[13];
  const float* W_ed1    = (const float*)d_in[14];
  const float* b_ed1    = (const float*)d_in[15];
  const float* W_ed2    = (const float*)d_in[16];
  const float* b_ed2    = (const float*)d_in[17];
  const float* W_en1    = (const float*)d_in[18];
  const float* b_en1    = (const float*)d_in[19];
  const float* W_en2    = (const float*)d_in[20];
  const float* b_en2    = (const float*)d_in[21];
  const float* W_st1    = (const float*)d_in[22];
  const float* b_st1    = (const float*)d_in[23];
  const float* W_st2    = (const float*)d_in[24];
  const float* b_st2    = (const float*)d_in[25];

  char* ws = (char*)d_ws;
  float*  Zt    = (float*)(ws + 0);          // 131072
  float*  Zb    = (float*)(ws + 131072);     // 131072
  float*  ZN    = (float*)(ws + 262144);     // 131072
  float*  Rt    = (float*)(ws + 393216);     // 786432
  __bf16* Bp    = (__bf16*)(ws + 1179648);   // 524288
  __bf16* Bp2   = (__bf16*)(ws + 1703936);   // 65536

  float* out_node = (float*)d_out;                 // 65536*4
  float* out_edge = out_node + 262144;             // 524288*3
  float* out_en   = out_node + 1835008;            // 256*2
  float* out_st   = out_node + 1835520;            // 256*9

  hipLaunchKernelGGL(k1_prep, dim3(400), dim3(256), 0, stream,
                     z, lattice, W_lat, b_lat, W_en1, b_en1, W_en2, b_en2,
                     W_st1, b_st1, W_st2, b_st2, W_nep, W_nd1, W_ed1,
                     Zt, Zb, ZN, Bp, Bp2, out_en, out_st);
  hipLaunchKernelGGL(k3_rtab, dim3(256), dim3(256), 0, stream,
                     Zt, Zb, b_ed1, W_ed2, b_ed2, Rt);
  hipLaunchKernelGGL(k4_edges, dim3(512), dim3(256), 0, stream,
                     src, dst, seg, Rt, out_edge);
  hipLaunchKernelGGL(k5_node, dim3(512), dim3(512), 0, stream,
                     node_emb, Bp, Bp2, seg, b_nep, b_nd1, W_nd2, b_nd2, ZN, out_node);
}

// Round 11
// 113.220 us; speedup vs baseline: 1.2221x; 1.0082x over previous
//
#include <hip/hip_runtime.h>
#include <hip/hip_bf16.h>

#define NN 65536
#define EE 524288
#define BB 256
#define LL 64
#define HH 128
#define DD2 256
#define NEF 1024

typedef __attribute__((ext_vector_type(4))) float f32x4;
typedef __attribute__((ext_vector_type(8))) __bf16 bf16x8;

__device__ __forceinline__ void gload_lds16(const void* g, void* l) {
  __builtin_amdgcn_global_load_lds(
      (__attribute__((address_space(1))) void*)(g),
      (__attribute__((address_space(3))) void*)(l), 16, 0, 0);
}

// K1: fused z-path + weight conversions (unchanged)
__global__ __launch_bounds__(256) void k1_prep(
    const float* __restrict__ z, const float* __restrict__ lattice,
    const float* __restrict__ W_lat, const float* __restrict__ b_lat,
    const float* __restrict__ W_en1, const float* __restrict__ b_en1,
    const float* __restrict__ W_en2, const float* __restrict__ b_en2,
    const float* __restrict__ W_st1, const float* __restrict__ b_st1,
    const float* __restrict__ W_st2, const float* __restrict__ b_st2,
    const float* __restrict__ W_nep, const float* __restrict__ W_nd1,
    const float* __restrict__ W_ed1,
    float* __restrict__ Zt, float* __restrict__ Zb, float* __restrict__ ZN,
    __bf16* __restrict__ Bp, __bf16* __restrict__ Bp2,
    float* __restrict__ out_en, float* __restrict__ out_st)
{
  int b = blockIdx.x, t = threadIdx.x;
  if (b < BB) {
    __shared__ float zl[70];
    __shared__ float zp[DD2];
    __shared__ float he[HH];
    __shared__ float hs[HH];
    if (t < LL) zl[t] = z[b*LL + t];
    else if (t < 70) zl[t] = lattice[t - LL];
    __syncthreads();
    {
      float acc = b_lat[t];
      #pragma unroll 4
      for (int k = 0; k < LL; ++k) acc = fmaf(zl[k], W_lat[k*DD2 + t], acc);
      zp[t] = fmaxf(acc, 0.f);
    }
    if (t < HH) {
      float a = b_en1[t];
      for (int k = 0; k < 70; ++k) a = fmaf(zl[k], W_en1[k*HH + t], a);
      he[t] = fmaxf(a, 0.f);
    } else {
      int tt = t - HH;
      float a = b_st1[tt];
      for (int k = 0; k < 70; ++k) a = fmaf(zl[k], W_st1[k*HH + tt], a);
      hs[tt] = fmaxf(a, 0.f);
    }
    __syncthreads();
    if (t < HH) {
      float a = 0.f, n = 0.f;
      #pragma unroll 4
      for (int k = 0; k < DD2; ++k) {
        a = fmaf(zp[k], W_ed1[k*HH + t], a);
        n = fmaf(zp[k], W_nd1[k*HH + t], n);
      }
      Zt[b*HH + t] = a;
      ZN[b*HH + t] = n;
    } else {
      int tt = t - HH;
      float a = 0.f;
      #pragma unroll 4
      for (int k = 0; k < DD2; ++k) a = fmaf(zp[k], W_ed1[(DD2 + k)*HH + tt], a);
      Zb[b*HH + tt] = a;
    }
    if (t < 2) {
      float a = b_en2[t];
      for (int k = 0; k < HH; ++k) a = fmaf(he[k], W_en2[k*2 + t], a);
      out_en[b*2 + t] = a;
    }
    if (t >= 32 && t < 41) {
      int c = t - 32;
      float a = b_st2[c];
      for (int k = 0; k < HH; ++k) a = fmaf(hs[k], W_st2[k*9 + c], a);
      out_st[b*9 + c] = a;
    }
  } else if (b < BB + 128) {           // W_nep (1024x256) -> Bp, kb = K-octet
    int kb = b - BB;                   // 0..127
    int col = t;
    bf16x8 v;
    #pragma unroll
    for (int j = 0; j < 8; ++j)
      v[j] = (__bf16)W_nep[(kb*8 + j)*256 + col];
    *(bf16x8*)(Bp + (kb*256 + col)*8) = v;
  } else {                             // W_nd1 (256x128) -> Bp2
    int kb = (b - BB - 128)*2 + (t >> 7);   // 0..31
    int col = t & 127;
    bf16x8 v;
    #pragma unroll
    for (int j = 0; j < 8; ++j)
      v[j] = (__bf16)W_nd1[(kb*8 + j)*128 + col];
    *(bf16x8*)(Bp2 + (kb*128 + col)*8) = v;
  }
}

// K3: R[gs][gd][c] = relu(Zt[gs]+Zb[gd]+b_ed1) @ W_ed2 + b_ed2   (256x256x3 table)
__global__ __launch_bounds__(256) void k3_rtab(
    const float* __restrict__ Zt, const float* __restrict__ Zb,
    const float* __restrict__ b_ed1, const float* __restrict__ W_ed2,
    const float* __restrict__ b_ed2, float* __restrict__ R)
{
  int gs = blockIdx.x, gd = threadIdx.x;
  __shared__ float zt_s[HH];
  __shared__ float b1_s[HH];
  __shared__ float w2_s[HH*3];
  if (gd < HH) {
    zt_s[gd] = Zt[gs*HH + gd];
    b1_s[gd] = b_ed1[gd];
    w2_s[gd] = W_ed2[gd];
    w2_s[gd + HH] = W_ed2[gd + HH];
    w2_s[gd + 2*HH] = W_ed2[gd + 2*HH];
  }
  __syncthreads();
  float a0 = b_ed2[0], a1 = b_ed2[1], a2 = b_ed2[2];
  const float* zbrow = Zb + gd*HH;
  #pragma unroll 4
  for (int k = 0; k < HH; ++k) {
    float h = fmaxf(zt_s[k] + zbrow[k] + b1_s[k], 0.f);
    a0 = fmaf(h, w2_s[k*3 + 0], a0);
    a1 = fmaf(h, w2_s[k*3 + 1], a1);
    a2 = fmaf(h, w2_s[k*3 + 2], a2);
  }
  float* o = R + (gs*256 + gd)*3;
  o[0] = a0; o[1] = a1; o[2] = a2;
}

// K4: recon_edge[e] = R[seg[src[e]]][seg[dst[e]]], 4 edges per thread
__global__ __launch_bounds__(256) void k4_edges(
    const int* __restrict__ src, const int* __restrict__ dst,
    const int* __restrict__ seg, const float* __restrict__ R,
    float* __restrict__ out_edge)
{
  int i = blockIdx.x*256 + threadIdx.x;              // 131072 threads
  int4 s4 = ((const int4*)src)[i];
  int4 d4 = ((const int4*)dst)[i];
  int b0 = (seg[s4.x]*256 + seg[d4.x])*3;
  int b1 = (seg[s4.y]*256 + seg[d4.y])*3;
  int b2 = (seg[s4.z]*256 + seg[d4.z])*3;
  int b3 = (seg[s4.w]*256 + seg[d4.w])*3;
  float r00 = R[b0], r01 = R[b0+1], r02 = R[b0+2];
  float r10 = R[b1], r11 = R[b1+1], r12 = R[b1+2];
  float r20 = R[b2], r21 = R[b2+1], r22 = R[b2+2];
  float r30 = R[b3], r31 = R[b3+1], r32 = R[b3+2];
  f32x4* o = (f32x4*)(out_edge + (size_t)i*12);
  f32x4 v0 = { r00, r01, r02, r10 };
  f32x4 v1 = { r11, r12, r20, r21 };
  f32x4 v2 = { r22, r30, r31, r32 };
  o[0] = v0; o[1] = v1; o[2] = v2;
}

// K5: fused node path. 512 threads / 8 waves (4 row-groups x 2 col-halves),
// wave = 32r x 128c. A: LDS TRIPLE buffer (XOR-swizzled, staged 2 ahead);
// B: LDS double buffer (staged 1 ahead). Counted vmcnt(2) per step.
// LDS = 3*16K(A) + 2*16K(B) = 80KB union nep tile -> 2 blocks/CU, 4 waves/SIMD.
__global__ __launch_bounds__(512, 4) void k5_node(
    const float* __restrict__ node_emb, const __bf16* __restrict__ Bp,
    const __bf16* __restrict__ Bp2, const int* __restrict__ seg,
    const float* __restrict__ b_nep, const float* __restrict__ b_nd1,
    const float* __restrict__ W_nd2, const float* __restrict__ b_nd2,
    const float* __restrict__ ZN, float* __restrict__ out_node)
{
  // [0,49152): A triple buffer; [49152,81920): B double buffer; union: nep 67584B
  __shared__ __align__(16) char lds_raw[81920];
  __bf16* nep_s = (__bf16*)lds_raw;

  const int tid = threadIdx.x;           // 0..511
  const int w   = tid >> 6;              // 0..7
  const int l15 = tid & 15;
  const int g4  = (tid >> 4) & 3;        // K-octet group
  const int wr  = w >> 1;                // row-group 0..3
  const int wc  = w & 1;                 // col-half 0..1
  const int rowbase = blockIdx.x * 128;

  f32x4 acc[2][8];
  const f32x4 fzero = {0.f, 0.f, 0.f, 0.f};
  #pragma unroll
  for (int rt = 0; rt < 2; ++rt)
    #pragma unroll
    for (int ct = 0; ct < 8; ++ct) acc[rt][ct] = fzero;

  // A staging pre-swizzle: physical LDS byte P = tid*16 (+8192*i),
  // logical byte = P ^ ((row&7)<<4), row = P>>7 = (tid>>3)+64i.
  const int arow_t = tid >> 3;                          // 0..63
  const int aoff   = (((tid & 7) ^ (arow_t & 7)) << 2); // f32 idx within row-step
  const int axor   = (l15 & 7) << 4;                    // read-side swizzle

  #define CVT8(DST, LO, HI)                                                     \
  { f32x4 lo_ = (LO), hi_ = (HI);                                               \
    DST[0]=(__bf16)lo_[0]; DST[1]=(__bf16)lo_[1]; DST[2]=(__bf16)lo_[2]; DST[3]=(__bf16)lo_[3]; \
    DST[4]=(__bf16)hi_[0]; DST[5]=(__bf16)hi_[1]; DST[6]=(__bf16)hi_[2]; DST[7]=(__bf16)hi_[3]; }

  #define STAGE_B(KB, BUF)                                                      \
  {                                                                             \
    int kb_ = (KB) > 31 ? 31 : (KB);                                            \
    char* Bd = lds_raw + 49152 + (BUF)*16384;                                   \
    const __bf16* bsrc = Bp + (size_t)kb_*8192 + tid*8;                         \
    gload_lds16(bsrc,        Bd + tid*16);                                      \
    gload_lds16(bsrc + 4096, Bd + tid*16 + 8192);                               \
  }

  #define STAGE_A(KB, BUF)                                                      \
  {                                                                             \
    int kb_ = (KB) > 31 ? 31 : (KB);                                            \
    char* Ad = lds_raw + (BUF)*16384;                                           \
    const float* asrc = node_emb + (size_t)rowbase*NEF + kb_*32 + aoff;         \
    gload_lds16(asrc + (size_t)arow_t*NEF,        Ad + tid*16);                 \
    gload_lds16(asrc + (size_t)(arow_t + 64)*NEF, Ad + tid*16 + 8192);          \
  }

  // ---- prologue: B(0)->b0, A(0)->a0, A(1)->a1; wait {B0,A0} (leave A1); barrier
  STAGE_B(0, 0);
  STAGE_A(0, 0);
  STAGE_A(1, 1);
  __builtin_amdgcn_sched_barrier(0);
  asm volatile("s_waitcnt vmcnt(2)" ::: "memory");
  __builtin_amdgcn_s_barrier();
  __builtin_amdgcn_sched_barrier(0);

  int aR = 0;   // A buffer being read (= kk%3)
  int aW = 2;   // A buffer receiving A(kk+2) (= (kk+2)%3)

  #pragma unroll 2
  for (int kk = 0; kk < 32; ++kk) {
    const int c = kk & 1;
    // issue: B(t+1) first, then A(t+2)  (order matters for the counted drain)
    STAGE_B(kk + 1, c ^ 1);
    STAGE_A(kk + 2, aW);
    __builtin_amdgcn_sched_barrier(0);
    // compute from A buf aR, B buf c
    const char* Ab = lds_raw + aR*16384;
    const char* Bb = lds_raw + 49152 + c*16384;
    int p0 = (((wr*32 + l15)*128)      + g4*32) ^ axor;
    int p1 = (((wr*32 + 16 + l15)*128) + g4*32) ^ axor;
    f32x4 a00 = *(const f32x4*)(Ab + p0);
    f32x4 a01 = *(const f32x4*)(Ab + (p0 ^ 16));
    f32x4 a10 = *(const f32x4*)(Ab + p1);
    f32x4 a11 = *(const f32x4*)(Ab + (p1 ^ 16));
    bf16x8 aa0, aa1;
    CVT8(aa0, a00, a01);
    CVT8(aa1, a10, a11);
    const bf16x8* Bv = (const bf16x8*)Bb;
    #pragma unroll
    for (int ct = 0; ct < 8; ++ct) {
      bf16x8 bfr = Bv[g4*256 + wc*128 + ct*16 + l15];
      acc[0][ct] = __builtin_amdgcn_mfma_f32_16x16x32_bf16(aa0, bfr, acc[0][ct], 0, 0, 0);
      acc[1][ct] = __builtin_amdgcn_mfma_f32_16x16x32_bf16(aa1, bfr, acc[1][ct], 0, 0, 0);
    }
    __builtin_amdgcn_sched_barrier(0);
    // drain {A(t+1), B(t+1)}; keep A(t+2) in flight
    asm volatile("s_waitcnt vmcnt(2)" ::: "memory");
    __builtin_amdgcn_s_barrier();
    __builtin_amdgcn_sched_barrier(0);
    aR = (aR == 2) ? 0 : aR + 1;
    aW = (aW == 2) ? 0 : aW + 1;
  }
  #undef STAGE_A
  #undef STAGE_B

  // drain the trailing A stage before nep_s overwrites the union
  asm volatile("s_waitcnt vmcnt(0)" ::: "memory");
  __syncthreads();

  // epilogue 1: nep = relu(acc + b_nep) -> LDS (bf16)
  #pragma unroll
  for (int rt = 0; rt < 2; ++rt)
    #pragma unroll
    for (int ct = 0; ct < 8; ++ct) {
      int col = wc*128 + ct*16 + l15;
      float bn = b_nep[col];
      #pragma unroll
      for (int r = 0; r < 4; ++r) {
        float v = fmaxf(acc[rt][ct][r] + bn, 0.f);
        int row = wr*32 + rt*16 + g4*4 + r;
        nep_s[row*264 + col] = (__bf16)v;
      }
    }
  __syncthreads();   // cross-wave: GEMM2 reads other waves' nep rows

  // GEMM2: h-pre = nep @ W_nd1 (K=256); wave w owns rows w*16..w*16+15
  f32x4 acc2[8];
  #pragma unroll
  for (int t = 0; t < 8; ++t) acc2[t] = fzero;
  const __bf16* nrow = nep_s + (w*16 + l15)*264 + g4*8;
  #pragma unroll 2
  for (int kk = 0; kk < 8; ++kk) {
    bf16x8 a2 = *(const bf16x8*)(nrow + kk*32);
    #pragma unroll
    for (int t = 0; t < 8; ++t) {
      bf16x8 b2 = *(const bf16x8*)(Bp2 + ((kk*4 + g4)*128 + t*16 + l15)*8);
      acc2[t] = __builtin_amdgcn_mfma_f32_16x16x32_bf16(a2, b2, acc2[t], 0, 0, 0);
    }
  }

  // epilogue 2: h = relu(acc2 + ZN[seg[row]] + b_nd1); recon = h @ W_nd2 + b_nd2
  int sid[4];
  #pragma unroll
  for (int r = 0; r < 4; ++r) sid[r] = seg[rowbase + w*16 + g4*4 + r];
  float p[4][4];
  #pragma unroll
  for (int r = 0; r < 4; ++r)
    #pragma unroll
    for (int c2 = 0; c2 < 4; ++c2) p[r][c2] = 0.f;
  #pragma unroll
  for (int t = 0; t < 8; ++t) {
    int col = t*16 + l15;
    float b1 = b_nd1[col];
    f32x4 w2 = *(const f32x4*)(W_nd2 + col*4);
    #pragma unroll
    for (int r = 0; r < 4; ++r) {
      float h = fmaxf(acc2[t][r] + ZN[sid[r]*HH + col] + b1, 0.f);
      p[r][0] = fmaf(h, w2[0], p[r][0]);
      p[r][1] = fmaf(h, w2[1], p[r][1]);
      p[r][2] = fmaf(h, w2[2], p[r][2]);
      p[r][3] = fmaf(h, w2[3], p[r][3]);
    }
  }
  #pragma unroll
  for (int off = 1; off < 16; off <<= 1)
    #pragma unroll
    for (int r = 0; r < 4; ++r)
      #pragma unroll
      for (int c2 = 0; c2 < 4; ++c2)
        p[r][c2] += __shfl_xor(p[r][c2], off, 64);
  if (l15 == 0) {
    f32x4 bn2 = *(const f32x4*)b_nd2;
    #pragma unroll
    for (int r = 0; r < 4; ++r) {
      f32x4 v = { p[r][0] + bn2[0], p[r][1] + bn2[1], p[r][2] + bn2[2], p[r][3] + bn2[3] };
      *(f32x4*)(out_node + (size_t)(rowbase + w*16 + g4*4 + r)*4) = v;
    }
  }
  #undef CVT8
}

extern "C" void kernel_launch(void* const* d_in, const int* in_sizes, int n_in,
                              void* d_out, int out_size, void* d_ws, size_t ws_size,
                              hipStream_t stream) {
  const float* z        = (const float*)d_in[0];
  const float* node_emb = (const float*)d_in[1];
  const float* lattice  = (const float*)d_in[2];
  const int*   seg      = (const int*)d_in[3];
  const int*   src      = (const int*)d_in[4];
  const int*   dst      = (const int*)d_in[5];
  const float* W_lat    = (const float*)d_in[6];
  const float* b_lat    = (const float*)d_in[7];
  const float* W_nep    = (const float*)d_in[8];
  const float* b_nep    = (const float*)d_in[9];
  const float* W_nd1    = (const float*)d_in[10];
  const float* b_nd1    = (const float*)d_in[11];
  const float* W_nd2    = (const float*)d_in[12];
  const float* b_nd2    = (const float*)d_in[13];
  const float* W_ed1    = (const float*)d_in[14];
  const float* b_ed1    = (const float*)d_in[15];
  const float* W_ed2    = (const float*)d_in[16];
  const float* b_ed2    = (const float*)d_in[17];
  const float* W_en1    = (const float*)d_in[18];
  const float* b_en1    = (const float*)d_in[19];
  const float* W_en2    = (const float*)d_in[20];
  const float* b_en2    = (const float*)d_in[21];
  const float* W_st1    = (const float*)d_in[22];
  const float* b_st1    = (const float*)d_in[23];
  const float* W_st2    = (const float*)d_in[24];
  const float* b_st2    = (const float*)d_in[25];

  char* ws = (char*)d_ws;
  float*  Zt    = (float*)(ws + 0);          // 131072
  float*  Zb    = (float*)(ws + 131072);     // 131072
  float*  ZN    = (float*)(ws + 262144);     // 131072
  float*  Rt    = (float*)(ws + 393216);     // 786432
  __bf16* Bp    = (__bf16*)(ws + 1179648);   // 524288
  __bf16* Bp2   = (__bf16*)(ws + 1703936);   // 65536

  float* out_node = (float*)d_out;                 // 65536*4
  float* out_edge = out_node + 262144;             // 524288*3
  float* out_en   = out_node + 1835008;            // 256*2
  float* out_st   = out_node + 1835520;            // 256*9

  hipLaunchKernelGGL(k1_prep, dim3(400), dim3(256), 0, stream,
                     z, lattice, W_lat, b_lat, W_en1, b_en1, W_en2, b_en2,
                     W_st1, b_st1, W_st2, b_st2, W_nep, W_nd1, W_ed1,
                     Zt, Zb, ZN, Bp, Bp2, out_en, out_st);
  hipLaunchKernelGGL(k3_rtab, dim3(256), dim3(256), 0, stream,
                     Zt, Zb, b_ed1, W_ed2, b_ed2, Rt);
  hipLaunchKernelGGL(k4_edges, dim3(512), dim3(256), 0, stream,
                     src, dst, seg, Rt, out_edge);
  hipLaunchKernelGGL(k5_node, dim3(512), dim3(512), 0, stream,
                     node_emb, Bp, Bp2, seg, b_nep, b_nd1, W_nd2, b_nd2, ZN, out_node);
}